// Round 11
// baseline (1829.915 us; speedup 1.0000x reference)
//
#include <hip/hip_runtime.h>
#include <hip/hip_cooperative_groups.h>
#include <math.h>

namespace cg = cooperative_groups;

#define B_N 128      // batch
#define NN 256       // n == m
#define DD 128       // feature dim
#define MAX_ITER 200
#define TOL 0.005f
#define BVAL (1.0f/256.0f)

__device__ __forceinline__ float wave_reduce_sum(float v) {
  #pragma unroll
  for (int off = 32; off >= 1; off >>= 1) v += __shfl_xor(v, off);
  return v;
}

// ---------------- K1: per-(b,d) normalization constant c = mean/sqrt(var+1e-4),
// plus zero-init of crit slots, pair flags, dmax, and dis accumulators. ----------------
__global__ __launch_bounds__(256) void prep_kernel(
    const float* __restrict__ X, const float* __restrict__ Y,
    float* __restrict__ cx, float* __restrict__ cy,
    int* __restrict__ dmax_i, float* __restrict__ crit_slots,
    int* __restrict__ flags, float* __restrict__ out) {
  int gid = blockIdx.x * 256 + threadIdx.x;          // 0..32767
  if (gid < 16) crit_slots[gid] = 0.0f;
  if (gid < 256) flags[gid] = 0;
  if (gid < B_N) { dmax_i[gid] = (int)0xFF800000; out[gid] = 0.0f; }  // -inf bits
  const float* src = (gid < 16384) ? X : Y;
  float* dst       = (gid < 16384) ? cx : cy;
  int g = gid & 16383;
  int b = g >> 7, d = g & 127;
  const float* p = src + ((size_t)b << 15) + d;      // b*256*128 + d
  float s = 0.f, ss = 0.f;
  #pragma unroll 8
  for (int i = 0; i < NN; i++) { float x = p[(size_t)i * DD]; s += x; ss = fmaf(x, x, ss); }
  float mean = s * (1.0f/256.0f);
  float var  = (ss - 256.0f * mean * mean) * (1.0f/255.0f);   // ddof=1
  dst[g] = mean / sqrtf(var + 1e-4f);
}

// ---------------- K2: dist[b][i][j] = sum_d (Xn - Yn)^2, tiled 64x64, + per-batch max ----------------
__global__ __launch_bounds__(256) void dist_kernel(
    const float* __restrict__ X, const float* __restrict__ Y,
    const float* __restrict__ cx, const float* __restrict__ cy,
    float* __restrict__ dist, int* __restrict__ dmax_i) {
  int b  = blockIdx.x;
  int i0 = blockIdx.y * 64, j0 = blockIdx.z * 64;
  __shared__ float xs[64][65], ys[64][65];
  __shared__ int bm;
  const float* Xb  = X + (size_t)b * (NN*DD);
  const float* Yb  = Y + (size_t)b * (NN*DD);
  const float* cxb = cx + b * DD;
  const float* cyb = cy + b * DD;
  if (threadIdx.x == 0) bm = (int)0xFF800000;
  float acc[4][4] = {};
  for (int dblk = 0; dblk < DD; dblk += 64) {
    for (int t = threadIdx.x; t < 1024; t += 256) {   // 64 rows x 16 float4
      int r = t >> 4, q = t & 15;
      float4 xv = ((const float4*)(Xb + (size_t)(i0 + r) * DD + dblk))[q];
      float4 cv = ((const float4*)(cxb + dblk))[q];
      xs[r][4*q+0] = xv.x - cv.x; xs[r][4*q+1] = xv.y - cv.y;
      xs[r][4*q+2] = xv.z - cv.z; xs[r][4*q+3] = xv.w - cv.w;
      float4 yv = ((const float4*)(Yb + (size_t)(j0 + r) * DD + dblk))[q];
      float4 dv = ((const float4*)(cyb + dblk))[q];
      ys[r][4*q+0] = yv.x - dv.x; ys[r][4*q+1] = yv.y - dv.y;
      ys[r][4*q+2] = yv.z - dv.z; ys[r][4*q+3] = yv.w - dv.w;
    }
    __syncthreads();
    int ti = threadIdx.x >> 4, tj = threadIdx.x & 15;
    #pragma unroll 4
    for (int d = 0; d < 64; d++) {
      float xr[4], yc[4];
      #pragma unroll
      for (int r = 0; r < 4; r++) xr[r] = xs[ti*4+r][d];
      #pragma unroll
      for (int c = 0; c < 4; c++) yc[c] = ys[tj*4+c][d];
      #pragma unroll
      for (int r = 0; r < 4; r++)
        #pragma unroll
        for (int c = 0; c < 4; c++) { float df = xr[r] - yc[c]; acc[r][c] = fmaf(df, df, acc[r][c]); }
    }
    __syncthreads();
  }
  int ti = threadIdx.x >> 4, tj = threadIdx.x & 15;
  float mx = -INFINITY;
  #pragma unroll
  for (int r = 0; r < 4; r++) {
    float4 o = make_float4(acc[r][0], acc[r][1], acc[r][2], acc[r][3]);
    ((float4*)(dist + ((size_t)b*NN + i0 + ti*4 + r) * NN + j0))[tj] = o;
    mx = fmaxf(mx, fmaxf(fmaxf(o.x, o.y), fmaxf(o.z, o.w)));
  }
  atomicMax(&bm, __float_as_int(mx));   // dist >= 0; max is large positive
  __syncthreads();
  if (threadIdx.x == 0) atomicMax(dmax_i + b, bm);
}

// ---------------- K3: k = p * exp((s - dist/dmax)*100), elementwise ----------------
__global__ __launch_bounds__(256) void kbuild_kernel(
    const float* __restrict__ dist, const int* __restrict__ dmax_i, float* __restrict__ kmat) {
  size_t id = (size_t)blockIdx.x * 256 + threadIdx.x;   // over 128*256*256
  int b = (int)(id >> 16);
  int rem = (int)(id & 65535);
  int i = rem >> 8, j = rem & 255;
  float inv = 1.0f / __int_as_float(dmax_i[b]);
  float d  = dist[id] * inv;
  float df = (float)(i - j);
  float p  = expf(df * df * (-1.0f/400.0f)) * 0.03989422804014327f; // 1/(10*sqrt(2*pi))
  float tt = df * (1.0f/256.0f);
  float s  = 0.1f / (tt * tt + 1.0f);
  kmat[id] = p * expf((s - d) * 100.0f);
}

// ---------------- K4: cooperative Sinkhorn, 2 blocks/batch, K fully in registers --------
// batch bb = blockIdx>>1, half h = blockIdx&1 owns rows [h*128, h*128+128).
// 16 waves/block; wave w owns 8 local rows [8w,8w+8). lane bits: lc=lane&15 (cols
// 16lc..16lc+16), lr=lane>>4; lane owns local rows 8w+2lr, 8w+2lr+1 -> Kreg[2][4] (8 VGPR).
// K^T u column partials are exchanged between the pair via agent-scope atomics in L2
// (seq-numbered flags, 2 data slots; both blocks run identical control flow).

__device__ __forceinline__ void mvT2(const float4 (&K)[2][4],
                                     const float* __restrict__ us_loc, int lrow0,
                                     int w, int lc, int lr, float pt[][NN]) {
  float u0 = us_loc[lrow0], u1 = us_loc[lrow0 + 1];
  float q[16];
  #pragma unroll
  for (int c4 = 0; c4 < 4; c4++) {
    q[4*c4+0] = fmaf(K[1][c4].x, u1, K[0][c4].x * u0);
    q[4*c4+1] = fmaf(K[1][c4].y, u1, K[0][c4].y * u0);
    q[4*c4+2] = fmaf(K[1][c4].z, u1, K[0][c4].z * u0);
    q[4*c4+3] = fmaf(K[1][c4].w, u1, K[0][c4].w * u0);
  }
  #pragma unroll
  for (int c = 0; c < 16; c++) {
    q[c] += __shfl_xor(q[c], 16);
    q[c] += __shfl_xor(q[c], 32);
  }
  if (lr == 0) {
    float4* dst = (float4*)&pt[w][lc * 16];
    dst[0] = make_float4(q[0],  q[1],  q[2],  q[3]);
    dst[1] = make_float4(q[4],  q[5],  q[6],  q[7]);
    dst[2] = make_float4(q[8],  q[9],  q[10], q[11]);
    dst[3] = make_float4(q[12], q[13], q[14], q[15]);
  }
}

__device__ __forceinline__ void mvN2(const float4 (&K)[2][4],
                                     const float* __restrict__ wsh, int col0,
                                     int lrow0, int lc, float* __restrict__ us_loc) {
  const float4* wv = (const float4*)(wsh + col0);
  float4 w0 = wv[0], w1 = wv[1], w2 = wv[2], w3 = wv[3];
  float p[2];
  #pragma unroll
  for (int r = 0; r < 2; r++) {
    float a = K[r][0].x * w0.x;
    a = fmaf(K[r][0].y, w0.y, a); a = fmaf(K[r][0].z, w0.z, a); a = fmaf(K[r][0].w, w0.w, a);
    float b2 = K[r][1].x * w1.x;
    b2 = fmaf(K[r][1].y, w1.y, b2); b2 = fmaf(K[r][1].z, w1.z, b2); b2 = fmaf(K[r][1].w, w1.w, b2);
    a = fmaf(K[r][2].x, w2.x, a);
    a = fmaf(K[r][2].y, w2.y, a); a = fmaf(K[r][2].z, w2.z, a); a = fmaf(K[r][2].w, w2.w, a);
    b2 = fmaf(K[r][3].x, w3.x, b2);
    b2 = fmaf(K[r][3].y, w3.y, b2); b2 = fmaf(K[r][3].z, w3.z, b2); b2 = fmaf(K[r][3].w, w3.w, b2);
    p[r] = a + b2;
  }
  #pragma unroll
  for (int r = 0; r < 2; r++) {
    p[r] += __shfl_xor(p[r], 1);
    p[r] += __shfl_xor(p[r], 2);
    p[r] += __shfl_xor(p[r], 4);
    p[r] += __shfl_xor(p[r], 8);
  }
  if (lc == 0) {
    us_loc[lrow0]     = 1.0f / (256.0f * p[0]);
    us_loc[lrow0 + 1] = 1.0f / (256.0f * p[1]);
  }
}

// column sum over the 16 wave-partials (stride-1KB rows: 2-way bank alias = free)
__device__ __forceinline__ float colsum16(const float pt[][NN], int j) {
  float a[16];
  #pragma unroll
  for (int w = 0; w < 16; w++) a[w] = pt[w][j];
  float s0 = (a[0]+a[1]) + (a[2]+a[3]);
  float s1 = (a[4]+a[5]) + (a[6]+a[7]);
  float s2 = (a[8]+a[9]) + (a[10]+a[11]);
  float s3 = (a[12]+a[13]) + (a[14]+a[15]);
  return (s0+s1) + (s2+s3);
}

__global__ void __launch_bounds__(1024)
sinkhorn_kernel(
    const float* __restrict__ kmat, float* __restrict__ u_g,
    float* __restrict__ v_g, float* __restrict__ crit_slots,
    float* __restrict__ exch, int* __restrict__ flags) {
  cg::grid_group grid = cg::this_grid();
  const int tid = threadIdx.x;
  const int w = tid >> 6, lane = tid & 63;
  const int lc = lane & 15, lr = lane >> 4;
  const int bb = blockIdx.x >> 1, h = blockIdx.x & 1;
  const int R0 = h * 128;                 // global row base of this block's half
  const int lrow0 = 8*w + 2*lr;           // lane's first local row
  const int col0 = 16*lc;
  const float* Kb = kmat + (size_t)bb * (NN*NN);
  float* emy = exch + (size_t)(bb*2 + h)     * 512;   // 2 slots x 256 floats
  float* eot = exch + (size_t)(bb*2 + (1-h)) * 512;
  int* fmy = flags + (bb*2 + h);
  int* fot = flags + (bb*2 + (1-h));

  __shared__ __align__(16) float us_loc[128], wsh[NN];
  __shared__ __align__(16) float ptb[16][NN];
  __shared__ float red[20];

  float4 Kreg[2][4];
  #pragma unroll
  for (int r = 0; r < 2; r++) {
    const float4* src = (const float4*)(Kb + (size_t)(R0 + lrow0 + r) * NN + col0);
    #pragma unroll
    for (int q = 0; q < 4; q++) Kreg[r][q] = src[q];
  }
  if (tid < 128) us_loc[tid] = BVAL;     // u0 = 1/n
  __syncthreads();

  int seq = 0;
  // colsum + pairwise exchange of the 256 column partials
  auto colsum_exchange = [&](int seqv, float& own, float& oth) {
    if (tid < NN) {
      own = colsum16(ptb, tid);
      __hip_atomic_store(emy + (seqv & 1) * 256 + tid, own,
                         __ATOMIC_RELAXED, __HIP_MEMORY_SCOPE_AGENT);
    }
    __syncthreads();                      // all slot stores complete before flag
    if (tid == 0) {
      __hip_atomic_store(fmy, seqv, __ATOMIC_RELEASE, __HIP_MEMORY_SCOPE_AGENT);
      while (__hip_atomic_load(fot, __ATOMIC_ACQUIRE, __HIP_MEMORY_SCOPE_AGENT) < seqv)
        __builtin_amdgcn_s_sleep(1);
    }
    __syncthreads();
    if (tid < NN)
      oth = __hip_atomic_load(eot + (seqv & 1) * 256 + tid,
                              __ATOMIC_RELAXED, __HIP_MEMORY_SCOPE_AGENT);
  };

  int compt = 0, check_idx = 0;
  bool done = false;
  while (!done && compt < MAX_ITER) {
    // ---- u1 = 1/(n * K @ (b / (K^T @ u))) ----
    mvT2(Kreg, us_loc, lrow0, w, lc, lr, ptb);
    __syncthreads();
    float own, oth;
    seq++;
    colsum_exchange(seq, own, oth);
    if (tid < NN) wsh[tid] = BVAL / (own + oth);
    __syncthreads();
    mvN2(Kreg, wsh, col0, lrow0, lc, us_loc);
    __syncthreads();
    int c1 = compt + 1;
    bool pred = ((c1 % 20) == 1) || (c1 == MAX_ITER);
    if (!pred) { compt = c1; continue; }
    // ---- convergence branch: v2 = b/(K^T u1) ----
    mvT2(Kreg, us_loc, lrow0, w, lc, lr, ptb);
    __syncthreads();
    seq++;
    colsum_exchange(seq, own, oth);
    if (tid < NN) wsh[tid] = BVAL / (own + oth);   // v2
    __syncthreads();
    // ---- u2 = 1/(n K v2) ----
    mvN2(Kreg, wsh, col0, lrow0, lc, us_loc);
    __syncthreads();
    // ---- crit = sum |v2 * (K^T u2) - b| ----
    mvT2(Kreg, us_loc, lrow0, w, lc, lr, ptb);
    __syncthreads();
    seq++;
    colsum_exchange(seq, own, oth);
    float cp = 0.f;
    if (tid < NN) cp = fabsf(wsh[tid] * (own + oth) - BVAL);
    cp = wave_reduce_sum(cp);
    if (lane == 0) red[w] = cp;
    __syncthreads();
    if (h == 0 && tid == 0)
      atomicAdd(&crit_slots[check_idx], red[0]+red[1]+red[2]+red[3]);
    grid.sync();
    if (tid == 0)
      red[16] = __hip_atomic_load(&crit_slots[check_idx], __ATOMIC_RELAXED, __HIP_MEMORY_SCOPE_AGENT);
    __syncthreads();
    float crit = red[16];
    check_idx++;
    bool conv = (crit < TOL) || isnan(crit);
    if (conv) { done = true; compt = c1; }
    else      { compt = c1 + 1; }
  }
  if (tid < 128) u_g[bb*NN + R0 + tid] = us_loc[tid];
  if (h == 0 && tid < NN) v_g[bb*NN + tid] = wsh[tid];  // loop always exits on a check
}

// ---------------- K5: dis[b] = sum_ij u*k*(dist/dmax)*v ; t = v^T * (u*k) ----------------
__global__ __launch_bounds__(256) void out_kernel(
    const float* __restrict__ kmat, const float* __restrict__ dist,
    const int* __restrict__ dmax_i, const float* __restrict__ u_g,
    const float* __restrict__ v_g, float* __restrict__ out) {
  int b = blockIdx.x;
  int tid = threadIdx.x, lane = tid & 63, wave = tid >> 6;
  __shared__ float vs[NN];
  __shared__ float usr[16];
  __shared__ float red[4];
  vs[tid] = v_g[b * NN + tid];
  if (tid < 16) usr[tid] = u_g[b * NN + blockIdx.y * 16 + tid];
  __syncthreads();
  float inv = 1.0f / __int_as_float(dmax_i[b]);
  float vj = vs[tid];
  const float* kb = kmat + (size_t)b * (NN*NN);
  const float* db = dist + (size_t)b * (NN*NN);
  float* tout = out + B_N + (size_t)b * (NN*NN);
  float dpart = 0.f;
  #pragma unroll 4
  for (int r = 0; r < 16; r++) {
    int i = blockIdx.y * 16 + r;
    float kv = kb[i * NN + tid];
    float ui = usr[r];
    float tv = (ui * kv) * vj;                 // v^T * (u*k)
    tout[i * NN + tid] = tv;
    dpart = fmaf(tv, db[i * NN + tid] * inv, dpart);   // u*k*d*v
  }
  dpart = wave_reduce_sum(dpart);
  if (lane == 0) red[wave] = dpart;
  __syncthreads();
  if (tid == 0) atomicAdd(out + b, red[0] + red[1] + red[2] + red[3]);
}

// ---------------- launch ----------------
extern "C" void kernel_launch(void* const* d_in, const int* in_sizes, int n_in,
                              void* d_out, int out_size, void* d_ws, size_t ws_size,
                              hipStream_t stream) {
  const float* X = (const float*)d_in[0];
  const float* Y = (const float*)d_in[1];
  float* out = (float*)d_out;
  char* ws = (char*)d_ws;
  // ws layout (bytes): dist 32MB | k 32MB | cx 64KB | cy 64KB | u 128KB | v 128KB |
  //                    dmax 512B | crit 64B | exch 512KB | flags 1KB
  float* dist  = (float*)(ws);
  float* kmat  = (float*)(ws + 33554432);
  float* cx    = (float*)(ws + 67108864);
  float* cy    = (float*)(ws + 67174400);
  float* u_g   = (float*)(ws + 67239936);
  float* v_g   = (float*)(ws + 67371008);
  int*   dmax  = (int*)  (ws + 67502080);
  float* crit  = (float*)(ws + 67502592);
  float* exch  = (float*)(ws + 67503104);
  int*   flags = (int*)  (ws + 68027392);

  hipLaunchKernelGGL(prep_kernel, dim3(128), dim3(256), 0, stream, X, Y, cx, cy, dmax, crit, flags, out);
  hipLaunchKernelGGL(dist_kernel, dim3(128, 4, 4), dim3(256), 0, stream, X, Y, cx, cy, dist, dmax);
  hipLaunchKernelGGL(kbuild_kernel, dim3(32768), dim3(256), 0, stream, dist, dmax, kmat);

  void* args[] = { (void*)&kmat, (void*)&u_g, (void*)&v_g, (void*)&crit, (void*)&exch, (void*)&flags };
  hipLaunchCooperativeKernel((void*)sinkhorn_kernel, dim3(256), dim3(1024), args, 0, stream);

  hipLaunchKernelGGL(out_kernel, dim3(128, 16), dim3(256), 0, stream, kmat, dist, dmax, u_g, v_g, out);
}

// Round 13
// 1194.826 us; speedup vs baseline: 1.5315x; 1.5315x over previous
//
#include <hip/hip_runtime.h>
#include <hip/hip_cooperative_groups.h>
#include <math.h>

namespace cg = cooperative_groups;

#define B_N 128      // batch
#define NN 256       // n == m
#define DD 128       // feature dim
#define MAX_ITER 200
#define TOL 0.005f
#define BVAL (1.0f/256.0f)

__device__ __forceinline__ float wave_reduce_sum(float v) {
  #pragma unroll
  for (int off = 32; off >= 1; off >>= 1) v += __shfl_xor(v, off);
  return v;
}

// ---------------- K1: per-(b,d) normalization constant c = mean/sqrt(var+1e-4),
// plus zero-init of crit slots, dmax, and the dis accumulators in d_out. ----------------
__global__ __launch_bounds__(256) void prep_kernel(
    const float* __restrict__ X, const float* __restrict__ Y,
    float* __restrict__ cx, float* __restrict__ cy,
    int* __restrict__ dmax_i, float* __restrict__ crit_slots,
    float* __restrict__ out) {
  int gid = blockIdx.x * 256 + threadIdx.x;          // 0..32767
  if (gid < 16) crit_slots[gid] = 0.0f;
  if (gid < B_N) { dmax_i[gid] = (int)0xFF800000; out[gid] = 0.0f; }  // -inf bits
  const float* src = (gid < 16384) ? X : Y;
  float* dst       = (gid < 16384) ? cx : cy;
  int g = gid & 16383;
  int b = g >> 7, d = g & 127;
  const float* p = src + ((size_t)b << 15) + d;      // b*256*128 + d
  float s = 0.f, ss = 0.f;
  #pragma unroll 8
  for (int i = 0; i < NN; i++) { float x = p[(size_t)i * DD]; s += x; ss = fmaf(x, x, ss); }
  float mean = s * (1.0f/256.0f);
  float var  = (ss - 256.0f * mean * mean) * (1.0f/255.0f);   // ddof=1
  dst[g] = mean / sqrtf(var + 1e-4f);
}

// ---------------- K2: dist[b][i][j] = sum_d (Xn - Yn)^2, tiled 64x64, + per-batch max ----------------
__global__ __launch_bounds__(256) void dist_kernel(
    const float* __restrict__ X, const float* __restrict__ Y,
    const float* __restrict__ cx, const float* __restrict__ cy,
    float* __restrict__ dist, int* __restrict__ dmax_i) {
  int b  = blockIdx.x;
  int i0 = blockIdx.y * 64, j0 = blockIdx.z * 64;
  __shared__ float xs[64][65], ys[64][65];
  __shared__ int bm;
  const float* Xb  = X + (size_t)b * (NN*DD);
  const float* Yb  = Y + (size_t)b * (NN*DD);
  const float* cxb = cx + b * DD;
  const float* cyb = cy + b * DD;
  if (threadIdx.x == 0) bm = (int)0xFF800000;
  float acc[4][4] = {};
  for (int dblk = 0; dblk < DD; dblk += 64) {
    for (int t = threadIdx.x; t < 1024; t += 256) {   // 64 rows x 16 float4
      int r = t >> 4, q = t & 15;
      float4 xv = ((const float4*)(Xb + (size_t)(i0 + r) * DD + dblk))[q];
      float4 cv = ((const float4*)(cxb + dblk))[q];
      xs[r][4*q+0] = xv.x - cv.x; xs[r][4*q+1] = xv.y - cv.y;
      xs[r][4*q+2] = xv.z - cv.z; xs[r][4*q+3] = xv.w - cv.w;
      float4 yv = ((const float4*)(Yb + (size_t)(j0 + r) * DD + dblk))[q];
      float4 dv = ((const float4*)(cyb + dblk))[q];
      ys[r][4*q+0] = yv.x - dv.x; ys[r][4*q+1] = yv.y - dv.y;
      ys[r][4*q+2] = yv.z - dv.z; ys[r][4*q+3] = yv.w - dv.w;
    }
    __syncthreads();
    int ti = threadIdx.x >> 4, tj = threadIdx.x & 15;
    #pragma unroll 4
    for (int d = 0; d < 64; d++) {
      float xr[4], yc[4];
      #pragma unroll
      for (int r = 0; r < 4; r++) xr[r] = xs[ti*4+r][d];
      #pragma unroll
      for (int c = 0; c < 4; c++) yc[c] = ys[tj*4+c][d];
      #pragma unroll
      for (int r = 0; r < 4; r++)
        #pragma unroll
        for (int c = 0; c < 4; c++) { float df = xr[r] - yc[c]; acc[r][c] = fmaf(df, df, acc[r][c]); }
    }
    __syncthreads();
  }
  int ti = threadIdx.x >> 4, tj = threadIdx.x & 15;
  float mx = -INFINITY;
  #pragma unroll
  for (int r = 0; r < 4; r++) {
    float4 o = make_float4(acc[r][0], acc[r][1], acc[r][2], acc[r][3]);
    ((float4*)(dist + ((size_t)b*NN + i0 + ti*4 + r) * NN + j0))[tj] = o;
    mx = fmaxf(mx, fmaxf(fmaxf(o.x, o.y), fmaxf(o.z, o.w)));
  }
  atomicMax(&bm, __float_as_int(mx));   // dist >= 0; max is large positive
  __syncthreads();
  if (threadIdx.x == 0) atomicMax(dmax_i + b, bm);
}

// ---------------- K3: k = p * exp((s - dist/dmax)*100), elementwise ----------------
__global__ __launch_bounds__(256) void kbuild_kernel(
    const float* __restrict__ dist, const int* __restrict__ dmax_i, float* __restrict__ kmat) {
  size_t id = (size_t)blockIdx.x * 256 + threadIdx.x;   // over 128*256*256
  int b = (int)(id >> 16);
  int rem = (int)(id & 65535);
  int i = rem >> 8, j = rem & 255;
  float inv = 1.0f / __int_as_float(dmax_i[b]);
  float d  = dist[id] * inv;
  float df = (float)(i - j);
  float p  = expf(df * df * (-1.0f/400.0f)) * 0.03989422804014327f; // 1/(10*sqrt(2*pi))
  float tt = df * (1.0f/256.0f);
  float s  = 0.1f / (tt * tt + 1.0f);
  kmat[id] = p * expf((s - d) * 100.0f);
}

// ---------------- K4: cooperative Sinkhorn, hybrid register/LDS K, conflict-free LDS ----
// 16 waves; wave w owns rows [16w,16w+16). lane = 16*lr+lc; lane's 4 rows: 16w+4lr+rr.
//   rr=0,1 -> Kreg[2][4] (32 VGPR);  rr=2,3 -> LDS.
// LDS layout (the R9 fix): lane-contiguous stages. Stage s = cc*2+rh (cc=col-quad,
// rh=row 2/3). kl[(w*8+s)*64 + lane] = K[16w+4lr+2+rh][16lc+4cc .. +4).
// Every ds_read_b128 is then a contiguous 1KB wave read -> zero bank conflicts
// (R9's layout had bank = (lc*4)%32 -> 8-way conflict on all 16 kl reads/iter).
__device__ __forceinline__ int klidx(int w, int s, int lane) {
  return ((w << 3) + s) * 64 + lane;
}

__device__ __forceinline__ void mvT(const float4 (&K)[2][4],
                                    const float4* __restrict__ kl,
                                    const float* __restrict__ us, int lrow0,
                                    int w, int lane, int lc, int lr,
                                    float pt[][NN]) {
  float4 uv = *(const float4*)(us + lrow0);
  float keep4[4];
  #pragma unroll
  for (int h = 0; h < 2; h++) {            // half h covers cc = 2h, 2h+1
    float q[8];
    #pragma unroll
    for (int c = 0; c < 8; c++) q[c] = 0.f;
    #pragma unroll
    for (int c4 = 0; c4 < 2; c4++) {
      int cc = 2*h + c4;
      float4 k0 = K[0][cc], k1 = K[1][cc];
      float4 l2 = kl[klidx(w, cc*2+0, lane)];
      float4 l3 = kl[klidx(w, cc*2+1, lane)];
      q[4*c4+0] = fmaf(l3.x, uv.w, fmaf(l2.x, uv.z, fmaf(k1.x, uv.y, k0.x * uv.x)));
      q[4*c4+1] = fmaf(l3.y, uv.w, fmaf(l2.y, uv.z, fmaf(k1.y, uv.y, k0.y * uv.x)));
      q[4*c4+2] = fmaf(l3.z, uv.w, fmaf(l2.z, uv.z, fmaf(k1.z, uv.y, k0.z * uv.x)));
      q[4*c4+3] = fmaf(l3.w, uv.w, fmaf(l2.w, uv.z, fmaf(k1.w, uv.y, k0.w * uv.x)));
    }
    #pragma unroll
    for (int c = 0; c < 8; c++) {
      q[c] += __shfl_xor(q[c], 16);
      q[c] += __shfl_xor(q[c], 32);
    }
    // lane keeps the 4 values it will write: half (lr>>1), quad (lr&1)
    if ((lr >> 1) == h) {
      keep4[0] = q[(lr & 1) * 4 + 0];
      keep4[1] = q[(lr & 1) * 4 + 1];
      keep4[2] = q[(lr & 1) * 4 + 2];
      keep4[3] = q[(lr & 1) * 4 + 3];
    }
  }
  // 64 lanes write 64 distinct float4s = contiguous 1KB -> conflict-free
  *(float4*)&pt[w][lc * 16 + lr * 4] = make_float4(keep4[0], keep4[1], keep4[2], keep4[3]);
}

__device__ __forceinline__ void mvN(const float4 (&K)[2][4],
                                    const float4* __restrict__ kl,
                                    const float* __restrict__ wsh, int col0,
                                    int lrow0, int w, int lane, int lc,
                                    float* __restrict__ us) {
  const float4* wv = (const float4*)(wsh + col0);
  float4 w0 = wv[0], w1 = wv[1], w2 = wv[2], w3 = wv[3];
  float p[4];
  #pragma unroll
  for (int r = 0; r < 2; r++) {
    float a = K[r][0].x * w0.x;
    a = fmaf(K[r][0].y, w0.y, a); a = fmaf(K[r][0].z, w0.z, a); a = fmaf(K[r][0].w, w0.w, a);
    float b2 = K[r][1].x * w1.x;
    b2 = fmaf(K[r][1].y, w1.y, b2); b2 = fmaf(K[r][1].z, w1.z, b2); b2 = fmaf(K[r][1].w, w1.w, b2);
    a = fmaf(K[r][2].x, w2.x, a);
    a = fmaf(K[r][2].y, w2.y, a); a = fmaf(K[r][2].z, w2.z, a); a = fmaf(K[r][2].w, w2.w, a);
    b2 = fmaf(K[r][3].x, w3.x, b2);
    b2 = fmaf(K[r][3].y, w3.y, b2); b2 = fmaf(K[r][3].z, w3.z, b2); b2 = fmaf(K[r][3].w, w3.w, b2);
    p[r] = a + b2;
  }
  #pragma unroll
  for (int rh = 0; rh < 2; rh++) {
    float4 L0 = kl[klidx(w, 0*2+rh, lane)];
    float4 L1 = kl[klidx(w, 1*2+rh, lane)];
    float4 L2 = kl[klidx(w, 2*2+rh, lane)];
    float4 L3 = kl[klidx(w, 3*2+rh, lane)];
    float a = L0.x * w0.x;
    a = fmaf(L0.y, w0.y, a); a = fmaf(L0.z, w0.z, a); a = fmaf(L0.w, w0.w, a);
    float b2 = L1.x * w1.x;
    b2 = fmaf(L1.y, w1.y, b2); b2 = fmaf(L1.z, w1.z, b2); b2 = fmaf(L1.w, w1.w, b2);
    a = fmaf(L2.x, w2.x, a);
    a = fmaf(L2.y, w2.y, a); a = fmaf(L2.z, w2.z, a); a = fmaf(L2.w, w2.w, a);
    b2 = fmaf(L3.x, w3.x, b2);
    b2 = fmaf(L3.y, w3.y, b2); b2 = fmaf(L3.z, w3.z, b2); b2 = fmaf(L3.w, w3.w, b2);
    p[2+rh] = a + b2;
  }
  #pragma unroll
  for (int r = 0; r < 4; r++) {
    p[r] += __shfl_xor(p[r], 1);
    p[r] += __shfl_xor(p[r], 2);
    p[r] += __shfl_xor(p[r], 4);
    p[r] += __shfl_xor(p[r], 8);
  }
  if (lc == 0) {
    *(float4*)(us + lrow0) = make_float4(1.0f/(256.0f*p[0]), 1.0f/(256.0f*p[1]),
                                         1.0f/(256.0f*p[2]), 1.0f/(256.0f*p[3]));
  }
}

// column sum over 16 wave-partials (per instr: 64 lanes x 4B consecutive = 2/bank = free)
__device__ __forceinline__ float colsum16(const float pt[][NN], int j) {
  float a[16];
  #pragma unroll
  for (int w = 0; w < 16; w++) a[w] = pt[w][j];
  float s0 = (a[0]+a[1]) + (a[2]+a[3]);
  float s1 = (a[4]+a[5]) + (a[6]+a[7]);
  float s2 = (a[8]+a[9]) + (a[10]+a[11]);
  float s3 = (a[12]+a[13]) + (a[14]+a[15]);
  return (s0+s1) + (s2+s3);
}

__global__ void __launch_bounds__(1024)
sinkhorn_kernel(
    const float* __restrict__ kmat, float* __restrict__ u_g,
    float* __restrict__ v_g, float* __restrict__ crit_slots) {
  cg::grid_group grid = cg::this_grid();
  const int tid = threadIdx.x;
  const int w = tid >> 6, lane = tid & 63;
  const int lc = lane & 15, lr = lane >> 4;
  const int b = blockIdx.x;
  const int lrow0 = 16*w + 4*lr;
  const int col0 = 16*lc;
  const float* Kb = kmat + (size_t)b * (NN*NN);
  __shared__ __align__(16) float us[NN], wsh[NN];
  __shared__ __align__(16) float pt[16][NN];
  __shared__ float red[20];
  __shared__ __align__(16) float4 kl[8192];   // 128 KB, lane-contiguous stages

  float4 Kreg[2][4];
  #pragma unroll
  for (int r = 0; r < 2; r++) {
    const float4* src = (const float4*)(Kb + (size_t)(lrow0 + r) * NN + col0);
    #pragma unroll
    for (int q = 0; q < 4; q++) Kreg[r][q] = src[q];
  }
  #pragma unroll
  for (int rh = 0; rh < 2; rh++) {
    #pragma unroll
    for (int cc = 0; cc < 4; cc++) {
      kl[klidx(w, cc*2+rh, lane)] =
        *(const float4*)(Kb + (size_t)(lrow0 + 2 + rh) * NN + col0 + 4*cc);
    }
  }
  if (tid < NN) us[tid] = BVAL;     // u0 = 1/n
  __syncthreads();

  int compt = 0, check_idx = 0;
  bool done = false;
  while (!done && compt < MAX_ITER) {
    // ---- u1 = 1/(n * K @ (b / (K^T @ u))) ----
    mvT(Kreg, kl, us, lrow0, w, lane, lc, lr, pt);
    __syncthreads();
    if (tid < NN) wsh[tid] = BVAL / colsum16(pt, tid);
    __syncthreads();
    mvN(Kreg, kl, wsh, col0, lrow0, w, lane, lc, us);
    __syncthreads();
    int c1 = compt + 1;
    bool pred = ((c1 % 20) == 1) || (c1 == MAX_ITER);
    if (!pred) { compt = c1; continue; }
    // ---- convergence branch: v2 = b/(K^T u1) ----
    mvT(Kreg, kl, us, lrow0, w, lane, lc, lr, pt);
    __syncthreads();
    if (tid < NN) wsh[tid] = BVAL / colsum16(pt, tid);   // v2
    __syncthreads();
    // ---- u2 = 1/(n K v2) ----
    mvN(Kreg, kl, wsh, col0, lrow0, w, lane, lc, us);
    __syncthreads();
    // ---- crit = sum |v2 * (K^T u2) - b| ----
    mvT(Kreg, kl, us, lrow0, w, lane, lc, lr, pt);
    __syncthreads();
    float cp = 0.f;
    if (tid < NN) {
      float tT3 = colsum16(pt, tid);
      cp = fabsf(wsh[tid] * tT3 - BVAL);
    }
    cp = wave_reduce_sum(cp);
    if (lane == 0) red[w] = cp;
    __syncthreads();
    if (tid == 0) atomicAdd(&crit_slots[check_idx], red[0]+red[1]+red[2]+red[3]);
    grid.sync();
    if (tid == 0)
      red[16] = __hip_atomic_load(&crit_slots[check_idx], __ATOMIC_RELAXED, __HIP_MEMORY_SCOPE_AGENT);
    __syncthreads();
    float crit = red[16];
    check_idx++;
    bool conv = (crit < TOL) || isnan(crit);
    if (conv) { done = true; compt = c1; }
    else      { compt = c1 + 1; }
  }
  if (tid < NN) {
    u_g[b*NN + tid] = us[tid];
    v_g[b*NN + tid] = wsh[tid];     // v only ever set at checks; loop always exits on a check
  }
}

// ---------------- K5: dis[b] = sum_ij u*k*(dist/dmax)*v ; t = v^T * (u*k) ----------------
__global__ __launch_bounds__(256) void out_kernel(
    const float* __restrict__ kmat, const float* __restrict__ dist,
    const int* __restrict__ dmax_i, const float* __restrict__ u_g,
    const float* __restrict__ v_g, float* __restrict__ out) {
  int b = blockIdx.x;
  int tid = threadIdx.x, lane = tid & 63, wave = tid >> 6;
  __shared__ float vs[NN];
  __shared__ float usr[16];
  __shared__ float red[4];
  vs[tid] = v_g[b * NN + tid];
  if (tid < 16) usr[tid] = u_g[b * NN + blockIdx.y * 16 + tid];
  __syncthreads();
  float inv = 1.0f / __int_as_float(dmax_i[b]);
  float vj = vs[tid];
  const float* kb = kmat + (size_t)b * (NN*NN);
  const float* db = dist + (size_t)b * (NN*NN);
  float* tout = out + B_N + (size_t)b * (NN*NN);
  float dpart = 0.f;
  #pragma unroll 4
  for (int r = 0; r < 16; r++) {
    int i = blockIdx.y * 16 + r;
    float kv = kb[i * NN + tid];
    float ui = usr[r];
    float tv = (ui * kv) * vj;                 // v^T * (u*k)
    tout[i * NN + tid] = tv;
    dpart = fmaf(tv, db[i * NN + tid] * inv, dpart);   // u*k*d*v
  }
  dpart = wave_reduce_sum(dpart);
  if (lane == 0) red[wave] = dpart;
  __syncthreads();
  if (tid == 0) atomicAdd(out + b, red[0] + red[1] + red[2] + red[3]);
}

// ---------------- launch ----------------
extern "C" void kernel_launch(void* const* d_in, const int* in_sizes, int n_in,
                              void* d_out, int out_size, void* d_ws, size_t ws_size,
                              hipStream_t stream) {
  const float* X = (const float*)d_in[0];
  const float* Y = (const float*)d_in[1];
  float* out = (float*)d_out;
  char* ws = (char*)d_ws;
  // ws layout (bytes): dist 32MB | k 32MB | cx 64KB | cy 64KB | u 128KB | v 128KB | dmax 512B | crit 64B
  float* dist  = (float*)(ws);
  float* kmat  = (float*)(ws + 33554432);
  float* cx    = (float*)(ws + 67108864);
  float* cy    = (float*)(ws + 67174400);
  float* u_g   = (float*)(ws + 67239936);
  float* v_g   = (float*)(ws + 67371008);
  int*   dmax  = (int*)  (ws + 67502080);
  float* crit  = (float*)(ws + 67502592);

  hipLaunchKernelGGL(prep_kernel, dim3(128), dim3(256), 0, stream, X, Y, cx, cy, dmax, crit, out);
  hipLaunchKernelGGL(dist_kernel, dim3(128, 4, 4), dim3(256), 0, stream, X, Y, cx, cy, dist, dmax);
  hipLaunchKernelGGL(kbuild_kernel, dim3(32768), dim3(256), 0, stream, dist, dmax, kmat);

  void* args[] = { (void*)&kmat, (void*)&u_g, (void*)&v_g, (void*)&crit };
  hipLaunchCooperativeKernel((void*)sinkhorn_kernel, dim3(128), dim3(1024), args, 0, stream);

  hipLaunchKernelGGL(out_kernel, dim3(128, 16), dim3(256), 0, stream, kmat, dist, dmax, u_g, v_g, out);
}